// Round 8
// baseline (205.186 us; speedup 1.0000x reference)
//
#include <hip/hip_runtime.h>
#include <math.h>

#define BB 1024
#define DD 128
#define QQ 65536
#define CHUNK 32
#define THREADS 256
#define NSLICES 256
#define SROWS (QQ / NSLICES)        // 256 rows per slice
#define NCHUNKS (SROWS / CHUNK)     // 8
#define CG 8                        // col groups (8 x 128 = 1024 cols)
#define HISTO_BLOCKS 64
#define INV_T 14.285714285714286f
#define SCALE 20.609929155556627f   // (1/T) * log2(e)
#define LN2F 0.6931471805599453f

typedef short short8 __attribute__((ext_vector_type(8)));
typedef float f32x4  __attribute__((ext_vector_type(4)));

#if __has_builtin(__builtin_amdgcn_exp2f)
#define EXP2F(x) __builtin_amdgcn_exp2f(x)
#else
#define EXP2F(x) exp2f(x)
#endif

static __device__ __forceinline__ unsigned short bf16rne(float f) {
    union { float f; unsigned u; } v; v.f = f;
    unsigned r = (v.u + 0x7FFFu + ((v.u >> 16) & 1u)) >> 16;
    return (unsigned short)r;
}

static __device__ __forceinline__ short8 pack8s(float4 x, float4 y) { // * SCALE
    short8 r;
    r[0]=(short)bf16rne(x.x*SCALE); r[1]=(short)bf16rne(x.y*SCALE);
    r[2]=(short)bf16rne(x.z*SCALE); r[3]=(short)bf16rne(x.w*SCALE);
    r[4]=(short)bf16rne(y.x*SCALE); r[5]=(short)bf16rne(y.y*SCALE);
    r[6]=(short)bf16rne(y.z*SCALE); r[7]=(short)bf16rne(y.w*SCALE);
    return r;
}
static __device__ __forceinline__ short8 pack8(float4 x, float4 y) { // unscaled
    short8 r;
    r[0]=(short)bf16rne(x.x); r[1]=(short)bf16rne(x.y);
    r[2]=(short)bf16rne(x.z); r[3]=(short)bf16rne(x.w);
    r[4]=(short)bf16rne(y.x); r[5]=(short)bf16rne(y.y);
    r[6]=(short)bf16rne(y.z); r[7]=(short)bf16rne(y.w);
    return r;
}

// ---------- prep: srr dots + f2bf (scaled bf16 of f2). 4 blocks x 256 ----------
template<int PRE>
__global__ __launch_bounds__(256)
void k_prep(const float* __restrict__ features,
            unsigned short* __restrict__ f2bf, float* __restrict__ srr)
{
    int r = blockIdx.x * 256 + threadIdx.x;      // 0..1023
    const float* f2p = features + (size_t)r * 2 * DD + DD;
    const float* f1p = features + (size_t)r * 2 * DD;
    float d = 0.f;
#pragma unroll
    for (int k = 0; k < DD / 8; ++k) {
        float4 a0 = reinterpret_cast<const float4*>(f2p)[2 * k];
        float4 a1 = reinterpret_cast<const float4*>(f2p)[2 * k + 1];
        float4 b0 = reinterpret_cast<const float4*>(f1p)[2 * k];
        float4 b1 = reinterpret_cast<const float4*>(f1p)[2 * k + 1];
        d += a0.x * b0.x + a0.y * b0.y + a0.z * b0.z + a0.w * b0.w;
        d += a1.x * b1.x + a1.y * b1.y + a1.z * b1.z + a1.w * b1.w;
        if (PRE)
            *reinterpret_cast<short8*>(f2bf + (size_t)r * DD + k * 8) = pack8s(a0, a1);
    }
    srr[r] = d;
}

// ---------- main: LDS-staged MFMA over one slice; first 64 blocks do histogram ----------
template<int PRE>
__global__ __launch_bounds__(THREADS, 6)
void supcon_main(const float* __restrict__ features, const int* __restrict__ labels,
                 const float* __restrict__ queue, const int* __restrict__ queue_labels,
                 const unsigned short* __restrict__ f2bf,
                 int* __restrict__ cnt, float* __restrict__ rowacc)
{
    const int bid0 = blockIdx.x;
    if (bid0 < HISTO_BLOCKS) {          // label histogram, output consumed by f_finish only
        int t = bid0 * 256 + threadIdx.x;          // 0..16383
#pragma unroll
        for (int k = 0; k < 4; ++k) {
            int idx = k * (HISTO_BLOCKS * 256) + t;
            int lab = (idx < BB) ? labels[idx] : queue_labels[idx - BB];
            atomicAdd(&cnt[lab], 1);
        }
        return;
    }
    const int bid = bid0 - HISTO_BLOCKS;
    const int slice = bid & (NSLICES - 1);         // (bid%8)==(slice%8): slice pinned to one XCD
    const int cg = bid >> 8;
    const int tid = threadIdx.x;
    const int l = tid & 63, w = tid >> 6;
    const int colbase = cg * 128 + w * 32;
    const int laneRow = l & 15, laneSeg = l >> 4;

    __shared__ int4 ldsbuf[2][512];   // 2 x 8KB bf16 A-chunks [32][128], XOR-swizzled

    // stationary B: 2x16 f2 cols, pre-scaled bf16
    short8 bf0[4], bf1[4];
    int mylab0, mylab1;
    {
        int r0 = colbase + laneRow, r1 = colbase + 16 + laneRow;
        mylab0 = labels[r0]; mylab1 = labels[r1];
        if (PRE) {
            const unsigned short* p0 = f2bf + (size_t)r0 * DD + laneSeg * 8;
            const unsigned short* p1 = f2bf + (size_t)r1 * DD + laneSeg * 8;
#pragma unroll
            for (int kk = 0; kk < 4; ++kk) {
                bf0[kk] = *reinterpret_cast<const short8*>(p0 + kk * 32);
                bf1[kk] = *reinterpret_cast<const short8*>(p1 + kk * 32);
            }
        } else {
            const float* p0 = features + (size_t)r0 * 2 * DD + DD + laneSeg * 8;
            const float* p1 = features + (size_t)r1 * 2 * DD + DD + laneSeg * 8;
#pragma unroll
            for (int kk = 0; kk < 4; ++kk) {
                bf0[kk] = pack8s(*reinterpret_cast<const float4*>(p0 + kk * 32),
                                 *reinterpret_cast<const float4*>(p0 + kk * 32 + 4));
                bf1[kk] = pack8s(*reinterpret_cast<const float4*>(p1 + kk * 32),
                                 *reinterpret_cast<const float4*>(p1 + kk * 32 + 4));
            }
        }
    }

    float tot0 = 0.f, tot1 = 0.f, pose0 = 0.f, pose1 = 0.f, psum0 = 0.f, psum1 = 0.f;

    // staging map: row = tid>>3 (0..31), seg = tid&7 (16 f32 each)
    const int srow_ = tid >> 3, sseg = tid & 7;
    const int swzs = (srow_ & 7) << 4;
    const int jbase = slice * SROWS;

    // prologue: stage chunk 0 (f32 -> bf16 in staging)
    {
        int j = jbase + srow_;
        const float* src = ((j < BB) ? (features + (size_t)j * 2 * DD)
                                     : (queue + (size_t)(j - BB) * DD)) + sseg * 16;
        float4 p0 = reinterpret_cast<const float4*>(src)[0];
        float4 p1 = reinterpret_cast<const float4*>(src)[1];
        float4 p2 = reinterpret_cast<const float4*>(src)[2];
        float4 p3 = reinterpret_cast<const float4*>(src)[3];
        char* base = (char*)&ldsbuf[0][0] + srow_ * 256;
        int cb0 = (sseg * 32) ^ swzs;
        *reinterpret_cast<short8*>(base + cb0)        = pack8(p0, p1);
        *reinterpret_cast<short8*>(base + (cb0 ^ 16)) = pack8(p2, p3);
    }

    int cur = 0;
    for (int c = 0; c < NCHUNKS; ++c) {
        __syncthreads();
        const int cj0 = jbase + c * CHUNK;
        const bool havenext = (c + 1 < NCHUNKS);

        // issue next chunk's global loads early (T14)
        float4 p0, p1, p2, p3;
        if (havenext) {
            int j = cj0 + CHUNK + srow_;
            const float* src = ((j < BB) ? (features + (size_t)j * 2 * DD)
                                         : (queue + (size_t)(j - BB) * DD)) + sseg * 16;
            p0 = reinterpret_cast<const float4*>(src)[0];
            p1 = reinterpret_cast<const float4*>(src)[1];
            p2 = reinterpret_cast<const float4*>(src)[2];
            p3 = reinterpret_cast<const float4*>(src)[3];
        }

        // compute from buf[cur]
        const char* abase = (const char*)&ldsbuf[cur][0];
#pragma unroll
        for (int t2 = 0; t2 < 2; ++t2) {
            const int row = t2 * 16 + laneRow;
            const char* rbase = abase + row * 256;
            const int g16 = laneSeg * 16;
            const int swz = (row & 7) << 4;
            short8 a0 = *reinterpret_cast<const short8*>(rbase + ((0   + g16) ^ swz));
            short8 a1 = *reinterpret_cast<const short8*>(rbase + ((64  + g16) ^ swz));
            short8 a2 = *reinterpret_cast<const short8*>(rbase + ((128 + g16) ^ swz));
            short8 a3 = *reinterpret_cast<const short8*>(rbase + ((192 + g16) ^ swz));

            const int j0 = cj0 + t2 * 16 + (laneSeg << 2);
            int4 ql4 = (j0 < BB) ? *reinterpret_cast<const int4*>(labels + j0)
                                 : *reinterpret_cast<const int4*>(queue_labels + (j0 - BB));
            const int* ql = reinterpret_cast<const int*>(&ql4);

            f32x4 acc0 = {0.f,0.f,0.f,0.f}, acc1 = {0.f,0.f,0.f,0.f};
            acc0 = __builtin_amdgcn_mfma_f32_16x16x32_bf16(a0, bf0[0], acc0, 0, 0, 0);
            acc1 = __builtin_amdgcn_mfma_f32_16x16x32_bf16(a0, bf1[0], acc1, 0, 0, 0);
            acc0 = __builtin_amdgcn_mfma_f32_16x16x32_bf16(a1, bf0[1], acc0, 0, 0, 0);
            acc1 = __builtin_amdgcn_mfma_f32_16x16x32_bf16(a1, bf1[1], acc1, 0, 0, 0);
            acc0 = __builtin_amdgcn_mfma_f32_16x16x32_bf16(a2, bf0[2], acc0, 0, 0, 0);
            acc1 = __builtin_amdgcn_mfma_f32_16x16x32_bf16(a2, bf1[2], acc1, 0, 0, 0);
            acc0 = __builtin_amdgcn_mfma_f32_16x16x32_bf16(a3, bf0[3], acc0, 0, 0, 0);
            acc1 = __builtin_amdgcn_mfma_f32_16x16x32_bf16(a3, bf1[3], acc1, 0, 0, 0);

#pragma unroll
            for (int reg = 0; reg < 4; ++reg) {
                float aa = acc0[reg];
                float e  = EXP2F(aa);                    // aa = s * log2(e)
                float pf = (ql[reg] == mylab0) ? 1.0f : 0.0f;
                tot0 += e;
                pose0 = fmaf(pf, e, pose0);
                psum0 = fmaf(pf, aa, psum0);
                float ab = acc1[reg];
                float eb = EXP2F(ab);
                float pg = (ql[reg] == mylab1) ? 1.0f : 0.0f;
                tot1 += eb;
                pose1 = fmaf(pg, eb, pose1);
                psum1 = fmaf(pg, ab, psum1);
            }
        }

        // write next chunk into the other buffer
        if (havenext) {
            char* base = (char*)&ldsbuf[cur ^ 1][0] + srow_ * 256;
            int cb0 = (sseg * 32) ^ swzs;
            *reinterpret_cast<short8*>(base + cb0)        = pack8(p0, p1);
            *reinterpret_cast<short8*>(base + (cb0 ^ 16)) = pack8(p2, p3);
            cur ^= 1;
        }
    }

    // reduce across the 4 lane-groups sharing each output col
#pragma unroll
    for (int off = 16; off <= 32; off <<= 1) {
        tot0  += __shfl_xor(tot0,  off);
        pose0 += __shfl_xor(pose0, off);
        psum0 += __shfl_xor(psum0, off);
        tot1  += __shfl_xor(tot1,  off);
        pose1 += __shfl_xor(pose1, off);
        psum1 += __shfl_xor(psum1, off);
    }
    if (l < 16) {
        float* d0 = rowacc + (size_t)(colbase + l) * 4;
        atomicAdd(d0 + 0, tot0);
        atomicAdd(d0 + 1, pose0);
        atomicAdd(d0 + 2, psum0);
        float* d1 = rowacc + (size_t)(colbase + 16 + l) * 4;
        atomicAdd(d1 + 0, tot1);
        atomicAdd(d1 + 1, pose1);
        atomicAdd(d1 + 2, psum1);
    }
}

// ---------- finish: per-row log terms, two scalars, last block writes out ----------
__global__ __launch_bounds__(256)
void f_finish(const float* __restrict__ rowacc, const float* __restrict__ srr,
              const int* __restrict__ cnt, const int* __restrict__ labels,
              float* __restrict__ scal, int* __restrict__ ticket,
              float* __restrict__ out)
{
    __shared__ float red[4][2];
    const int r = blockIdx.x * 256 + threadIdx.x;
    const int wv = threadIdx.x >> 6, lane = threadIdx.x & 63;

    float4 v = reinterpret_cast<const float4*>(rowacc)[r];
    float tot = v.x, pose = v.y, ps = v.z;
    float srow = srr[r] * INV_T;                 // exact diag logit
    float trip = srow - logf(tot - expf(srow));
    float wgt  = 1.f / (float)(cnt[labels[r]] - 1);
    float mlpp = (ps * LN2F - srow) * wgt - logf(tot - pose);

#pragma unroll
    for (int off = 32; off > 0; off >>= 1) {
        trip += __shfl_xor(trip, off);
        mlpp += __shfl_xor(mlpp, off);
    }
    if (lane == 0) { red[wv][0] = trip; red[wv][1] = mlpp; }
    __syncthreads();
    if (threadIdx.x == 0) {
        atomicAdd(&scal[0], red[0][0] + red[1][0] + red[2][0] + red[3][0]);
        atomicAdd(&scal[1], red[0][1] + red[1][1] + red[2][1] + red[3][1]);
        __threadfence();
        int old = atomicAdd(ticket, 1);
        if (old == 3) {
            float aT = atomicAdd(&scal[0], 0.f);
            float aM = atomicAdd(&scal[1], 0.f);
            float selfl  = -aT / (float)BB;
            float classl = -aM / (float)BB;
            out[0] = 0.5f * (selfl + classl);
            out[1] = selfl;
            out[2] = classl;
        }
    }
}

extern "C" void kernel_launch(void* const* d_in, const int* in_sizes, int n_in,
                              void* d_out, int out_size, void* d_ws, size_t ws_size,
                              hipStream_t stream)
{
    const float* features     = (const float*)d_in[0];
    const int*   labels       = (const int*)  d_in[1];
    const float* queue        = (const float*)d_in[2];
    const int*   queue_labels = (const int*)  d_in[3];
    char* ws = (char*)d_ws;

    // ws layout: [zeroed: cnt 4096 | scal 128 | ticket 128 | rowacc 16384]
    //            srr 4096 | f2bf 256KB
    const size_t cnt_off    = 0;
    const size_t scal_off   = 4096;
    const size_t ticket_off = 4096 + 128;
    const size_t rowacc_off = 4096 + 256;
    const size_t zero_sz    = rowacc_off + 16384;
    const size_t srr_off    = zero_sz;
    const size_t f2bf_off   = srr_off + 4096;
    const size_t f2bf_sz    = (size_t)BB * DD * 2;        // 256 KB
    const size_t total_pre  = f2bf_off + f2bf_sz;

    const bool pre = ws_size >= total_pre;

    int*   cnt    = (int*)(ws + cnt_off);
    float* scal   = (float*)(ws + scal_off);
    int*   ticket = (int*)(ws + ticket_off);
    float* rowacc = (float*)(ws + rowacc_off);
    float* srr    = (float*)(ws + srr_off);
    unsigned short* f2bf = pre ? (unsigned short*)(ws + f2bf_off) : nullptr;

    hipMemsetAsync(ws, 0, zero_sz, stream);

    if (pre) k_prep<1><<<dim3(4), dim3(256), 0, stream>>>(features, f2bf, srr);
    else     k_prep<0><<<dim3(4), dim3(256), 0, stream>>>(features, f2bf, srr);

    dim3 grid(HISTO_BLOCKS + CG * NSLICES);   // 64 histo blocks + 2048 main blocks
    if (pre)
        supcon_main<1><<<grid, dim3(THREADS), 0, stream>>>(
            features, labels, queue, queue_labels, f2bf, cnt, rowacc);
    else
        supcon_main<0><<<grid, dim3(THREADS), 0, stream>>>(
            features, labels, queue, queue_labels, f2bf, cnt, rowacc);

    f_finish<<<dim3(4), dim3(256), 0, stream>>>(
        rowacc, srr, cnt, labels, scal, ticket, (float*)d_out);
}

// Round 9
// 117.902 us; speedup vs baseline: 1.7403x; 1.7403x over previous
//
#include <hip/hip_runtime.h>
#include <math.h>

#define BB 1024
#define DD 128
#define QQ 65536
#define CHUNK 32
#define THREADS 256
#define NSLICES 256
#define SROWS (QQ / NSLICES)        // 256 rows per slice
#define NCHUNKS (SROWS / CHUNK)     // 8
#define CG 4                        // col groups (4 x 256 = 1024 cols)
#define INV_T 14.285714285714286f
#define SCALE 20.609929155556627f   // (1/T) * log2(e)
#define LN2F 0.6931471805599453f

typedef short short8 __attribute__((ext_vector_type(8)));
typedef float f32x4  __attribute__((ext_vector_type(4)));

typedef __attribute__((address_space(1))) const void GV;   // global
typedef __attribute__((address_space(3))) void LV;         // LDS

static __device__ __forceinline__ float fast_exp2(float x) {
    float r;
    asm("v_exp_f32 %0, %1" : "=v"(r) : "v"(x));
    return r;
}

static __device__ __forceinline__ unsigned short bf16rne(float f) {
    union { float f; unsigned u; } v; v.f = f;
    unsigned r = (v.u + 0x7FFFu + ((v.u >> 16) & 1u)) >> 16;
    return (unsigned short)r;
}

static __device__ __forceinline__ short8 pack8s(float4 x, float4 y) { // * SCALE
    short8 r;
    r[0]=(short)bf16rne(x.x*SCALE); r[1]=(short)bf16rne(x.y*SCALE);
    r[2]=(short)bf16rne(x.z*SCALE); r[3]=(short)bf16rne(x.w*SCALE);
    r[4]=(short)bf16rne(y.x*SCALE); r[5]=(short)bf16rne(y.y*SCALE);
    r[6]=(short)bf16rne(y.z*SCALE); r[7]=(short)bf16rne(y.w*SCALE);
    return r;
}
static __device__ __forceinline__ short8 pack8(float4 x, float4 y) { // unscaled
    short8 r;
    r[0]=(short)bf16rne(x.x); r[1]=(short)bf16rne(x.y);
    r[2]=(short)bf16rne(x.z); r[3]=(short)bf16rne(x.w);
    r[4]=(short)bf16rne(y.x); r[5]=(short)bf16rne(y.y);
    r[6]=(short)bf16rne(y.z); r[7]=(short)bf16rne(y.w);
    return r;
}

// ---------- conv: qbf (bf16, PRE-SWIZZLED) + qlabn + cnt histogram + srr + f2bf ----------
// blocks 0..511: 128 queue_new rows each (2 threads/row); also qlabn + histogram.
// blocks 512..515: srr dot + f2bf (scaled bf16 f2), one thread per batch row.
template<int PRE>
__global__ __launch_bounds__(256)
void k1_conv(const float* __restrict__ features, const int* __restrict__ labels,
             const float* __restrict__ queue, const int* __restrict__ queue_labels,
             unsigned short* __restrict__ qbf, int* __restrict__ qlabn,
             unsigned short* __restrict__ f2bf,
             int* __restrict__ cnt, float* __restrict__ srr)
{
    const int blk = blockIdx.x;
    const int t = threadIdx.x;
    if (blk < 512) {
        if (t < 128) {      // labels + histogram for this block's 128 rows
            int j2 = blk * 128 + t;
            int lab = (j2 < BB) ? labels[j2] : queue_labels[j2 - BB];
            if (PRE) qlabn[j2] = lab;
            atomicAdd(&cnt[lab], 1);
        }
        if (PRE) {
            const int j = blk * 128 + (t >> 1);     // row
            const int h = t & 1;                    // half: bf16 bytes [h*128, h*128+128)
            const unsigned swz = (unsigned)(j & 7) << 4;
            const char* srcb = (const char*)((j < BB)
                ? (features + (size_t)j * 2 * DD)    // f1 row
                : (queue + (size_t)(j - BB) * DD));
            char* dstrow = (char*)qbf + (size_t)j * 256;
#pragma unroll
            for (int k = 0; k < 8; ++k) {
                int p  = h * 128 + k * 16;          // storage byte pos (bf16)
                int cb = p ^ swz;                   // data byte pos   (bf16)
                const float4* s = reinterpret_cast<const float4*>(srcb + cb * 2);
                *reinterpret_cast<short8*>(dstrow + p) = pack8(s[0], s[1]);
            }
        }
    } else {
        int r = (blk - 512) * 256 + t;              // 0..1023
        const float* f2p = features + (size_t)r * 2 * DD + DD;
        const float* f1p = features + (size_t)r * 2 * DD;
        float d = 0.f;
#pragma unroll
        for (int k = 0; k < DD / 8; ++k) {
            float4 a0 = reinterpret_cast<const float4*>(f2p)[2 * k];
            float4 a1 = reinterpret_cast<const float4*>(f2p)[2 * k + 1];
            float4 b0 = reinterpret_cast<const float4*>(f1p)[2 * k];
            float4 b1 = reinterpret_cast<const float4*>(f1p)[2 * k + 1];
            d += a0.x * b0.x + a0.y * b0.y + a0.z * b0.z + a0.w * b0.w;
            d += a1.x * b1.x + a1.y * b1.y + a1.z * b1.z + a1.w * b1.w;
            if (PRE)
                *reinterpret_cast<short8*>(f2bf + (size_t)r * DD + k * 8) = pack8s(a0, a1);
        }
        srr[r] = d;
    }
}

// ---------- main: LDS double-buffer via global_load_lds (PRE) ----------
// grid: CG x NSLICES; block = 4 waves; wave = 64 cols (4 x 16-col B frags) x slice rows.
template<int PRE>
__global__ __launch_bounds__(THREADS)
void supcon_main(const float* __restrict__ features, const int* __restrict__ labels,
                 const float* __restrict__ queue, const int* __restrict__ queue_labels,
                 const unsigned short* __restrict__ qbf, const int* __restrict__ qlabn,
                 const unsigned short* __restrict__ f2bf,
                 float* __restrict__ rowacc)
{
    __shared__ int4 ldsbuf[2][512];   // 2 x 8KB bf16 chunks [32 rows][256B], swizzled

    const int tid = threadIdx.x;
    const int l = tid & 63, w = tid >> 6;
    const int bid = blockIdx.x;
    const int slice = bid & (NSLICES - 1);   // bid%8 == slice%8: slice pinned to one XCD
    const int cg = bid >> 8;
    const int colbase = cg * 256 + w * 64;
    const int laneRow = l & 15, laneSeg = l >> 4;
    const int jbase = slice * SROWS;

    // stationary B: 4x16 f2 cols, pre-scaled bf16
    short8 bf[4][4];
    int mylab[4];
#pragma unroll
    for (int b = 0; b < 4; ++b) {
        int r = colbase + b * 16 + laneRow;
        mylab[b] = labels[r];
        if (PRE) {
            const unsigned short* fp = f2bf + (size_t)r * DD + laneSeg * 8;
#pragma unroll
            for (int kk = 0; kk < 4; ++kk)
                bf[b][kk] = *reinterpret_cast<const short8*>(fp + kk * 32);
        } else {
            const float* fp = features + (size_t)r * 2 * DD + DD + laneSeg * 8;
#pragma unroll
            for (int kk = 0; kk < 4; ++kk)
                bf[b][kk] = pack8s(*reinterpret_cast<const float4*>(fp + kk * 32),
                                   *reinterpret_cast<const float4*>(fp + kk * 32 + 4));
        }
    }

    float tot[4]  = {0.f,0.f,0.f,0.f};
    float pose[4] = {0.f,0.f,0.f,0.f};
    float psum[4] = {0.f,0.f,0.f,0.f};

    // non-PRE staging map (reg path): row = tid>>3, seg = tid&7
    const int srow_ = tid >> 3, sseg = tid & 7;
    const int swzs = (srow_ & 7) << 4;

    // ---- staging helpers ----
    // PRE: qbf is pre-swizzled; linear copy of 8KB chunk via global_load_lds.
    // wave w covers bytes [w*2048, w*2048+2048) in two 1KB instructions.
#define STAGE_PRE(nb, c)                                                          \
    {                                                                             \
        const char* gs = (const char*)qbf + (size_t)(jbase + (c) * CHUNK) * 256   \
                         + w * 2048 + l * 16;                                     \
        char* ls = (char*)&ldsbuf[nb][0] + w * 2048;                              \
        __builtin_amdgcn_global_load_lds((GV*)gs, (LV*)ls, 16, 0, 0);             \
        __builtin_amdgcn_global_load_lds((GV*)(gs + 1024), (LV*)(ls + 1024), 16, 0, 0); \
    }

    if (PRE) {
        STAGE_PRE(0, 0);
    } else {
        int j = jbase + srow_;
        const float* src = ((j < BB) ? (features + (size_t)j * 2 * DD)
                                     : (queue + (size_t)(j - BB) * DD)) + sseg * 16;
        float4 p0 = reinterpret_cast<const float4*>(src)[0];
        float4 p1 = reinterpret_cast<const float4*>(src)[1];
        float4 p2 = reinterpret_cast<const float4*>(src)[2];
        float4 p3 = reinterpret_cast<const float4*>(src)[3];
        char* base = (char*)&ldsbuf[0][0] + srow_ * 256;
        int cb0 = (sseg * 32) ^ swzs;
        *reinterpret_cast<short8*>(base + cb0)        = pack8(p0, p1);
        *reinterpret_cast<short8*>(base + (cb0 ^ 16)) = pack8(p2, p3);
    }

    int cur = 0;
    for (int c = 0; c < NCHUNKS; ++c) {
        __syncthreads();                      // buf[cur] ready; prior reads of buf[cur^1] done
        const int cj0 = jbase + c * CHUNK;
        const bool havenext = (c + 1 < NCHUNKS);

        float4 p0, p1, p2, p3;
        if (havenext) {
            if (PRE) {
                STAGE_PRE(cur ^ 1, c + 1);    // async into other buffer, lands by next barrier
            } else {
                int j = cj0 + CHUNK + srow_;
                const float* src = ((j < BB) ? (features + (size_t)j * 2 * DD)
                                             : (queue + (size_t)(j - BB) * DD)) + sseg * 16;
                p0 = reinterpret_cast<const float4*>(src)[0];
                p1 = reinterpret_cast<const float4*>(src)[1];
                p2 = reinterpret_cast<const float4*>(src)[2];
                p3 = reinterpret_cast<const float4*>(src)[3];
            }
        }

        // compute from buf[cur]
        const char* abase = (const char*)&ldsbuf[cur][0];
#pragma unroll
        for (int t2 = 0; t2 < 2; ++t2) {
            const int row = t2 * 16 + laneRow;
            const char* rbase = abase + row * 256;
            const int g16 = laneSeg * 16;
            const int swz = (row & 7) << 4;
            short8 a0 = *reinterpret_cast<const short8*>(rbase + ((0   + g16) ^ swz));
            short8 a1 = *reinterpret_cast<const short8*>(rbase + ((64  + g16) ^ swz));
            short8 a2 = *reinterpret_cast<const short8*>(rbase + ((128 + g16) ^ swz));
            short8 a3 = *reinterpret_cast<const short8*>(rbase + ((192 + g16) ^ swz));

            const int j0 = cj0 + t2 * 16 + (laneSeg << 2);
            int4 ql4;
            if (PRE) ql4 = *reinterpret_cast<const int4*>(qlabn + j0);
            else ql4 = (j0 < BB) ? *reinterpret_cast<const int4*>(labels + j0)
                                 : *reinterpret_cast<const int4*>(queue_labels + (j0 - BB));
            const int* ql = reinterpret_cast<const int*>(&ql4);

            f32x4 acc[4];
#pragma unroll
            for (int b = 0; b < 4; ++b) {
                acc[b] = f32x4{0.f,0.f,0.f,0.f};
                acc[b] = __builtin_amdgcn_mfma_f32_16x16x32_bf16(a0, bf[b][0], acc[b], 0, 0, 0);
                acc[b] = __builtin_amdgcn_mfma_f32_16x16x32_bf16(a1, bf[b][1], acc[b], 0, 0, 0);
                acc[b] = __builtin_amdgcn_mfma_f32_16x16x32_bf16(a2, bf[b][2], acc[b], 0, 0, 0);
                acc[b] = __builtin_amdgcn_mfma_f32_16x16x32_bf16(a3, bf[b][3], acc[b], 0, 0, 0);
            }
#pragma unroll
            for (int b = 0; b < 4; ++b) {
#pragma unroll
                for (int reg = 0; reg < 4; ++reg) {
                    float aa = acc[b][reg];
                    float e  = fast_exp2(aa);             // aa = s * log2(e)
                    float pf = (ql[reg] == mylab[b]) ? 1.0f : 0.0f;
                    tot[b]  += e;
                    pose[b]  = fmaf(pf, e, pose[b]);
                    psum[b]  = fmaf(pf, aa, psum[b]);
                }
            }
        }

        if (havenext && !PRE) {
            char* base = (char*)&ldsbuf[cur ^ 1][0] + srow_ * 256;
            int cb0 = (sseg * 32) ^ swzs;
            *reinterpret_cast<short8*>(base + cb0)        = pack8(p0, p1);
            *reinterpret_cast<short8*>(base + (cb0 ^ 16)) = pack8(p2, p3);
        }
        cur ^= 1;
    }

    // reduce across the 4 lane-groups sharing each output col
#pragma unroll
    for (int b = 0; b < 4; ++b) {
#pragma unroll
        for (int off = 16; off <= 32; off <<= 1) {
            tot[b]  += __shfl_xor(tot[b],  off);
            pose[b] += __shfl_xor(pose[b], off);
            psum[b] += __shfl_xor(psum[b], off);
        }
    }
    if (l < 16) {
#pragma unroll
        for (int b = 0; b < 4; ++b) {
            float* d = rowacc + (size_t)(colbase + b * 16 + l) * 4;
            atomicAdd(d + 0, tot[b]);
            atomicAdd(d + 1, pose[b]);
            atomicAdd(d + 2, psum[b]);
        }
    }
}

// ---------- finish: per-row log terms, two scalars, last block writes out ----------
__global__ __launch_bounds__(256)
void f_finish(const float* __restrict__ rowacc, const float* __restrict__ srr,
              const int* __restrict__ cnt, const int* __restrict__ labels,
              float* __restrict__ scal, int* __restrict__ ticket,
              float* __restrict__ out)
{
    __shared__ float red[4][2];
    const int r = blockIdx.x * 256 + threadIdx.x;
    const int wv = threadIdx.x >> 6, lane = threadIdx.x & 63;

    float4 v = reinterpret_cast<const float4*>(rowacc)[r];
    float tot = v.x, pose = v.y, ps = v.z;
    float srow = srr[r] * INV_T;                 // exact diag logit
    float trip = srow - logf(tot - expf(srow));
    float wgt  = 1.f / (float)(cnt[labels[r]] - 1);
    float mlpp = (ps * LN2F - srow) * wgt - logf(tot - pose);

#pragma unroll
    for (int off = 32; off > 0; off >>= 1) {
        trip += __shfl_xor(trip, off);
        mlpp += __shfl_xor(mlpp, off);
    }
    if (lane == 0) { red[wv][0] = trip; red[wv][1] = mlpp; }
    __syncthreads();
    if (threadIdx.x == 0) {
        atomicAdd(&scal[0], red[0][0] + red[1][0] + red[2][0] + red[3][0]);
        atomicAdd(&scal[1], red[0][1] + red[1][1] + red[2][1] + red[3][1]);
        __threadfence();
        int old = atomicAdd(ticket, 1);
        if (old == 3) {
            float aT = atomicAdd(&scal[0], 0.f);
            float aM = atomicAdd(&scal[1], 0.f);
            float selfl  = -aT / (float)BB;
            float classl = -aM / (float)BB;
            out[0] = 0.5f * (selfl + classl);
            out[1] = selfl;
            out[2] = classl;
        }
    }
}

extern "C" void kernel_launch(void* const* d_in, const int* in_sizes, int n_in,
                              void* d_out, int out_size, void* d_ws, size_t ws_size,
                              hipStream_t stream)
{
    const float* features     = (const float*)d_in[0];
    const int*   labels       = (const int*)  d_in[1];
    const float* queue        = (const float*)d_in[2];
    const int*   queue_labels = (const int*)  d_in[3];
    char* ws = (char*)d_ws;

    // ws layout: [zeroed: cnt 4096 | scal 128 | ticket 128 | rowacc 16384]
    //            srr 4096 | f2bf 256KB | qbf 16MB | qlabn 256KB
    const size_t cnt_off    = 0;
    const size_t scal_off   = 4096;
    const size_t ticket_off = 4096 + 128;
    const size_t rowacc_off = 4096 + 256;
    const size_t zero_sz    = rowacc_off + 16384;
    const size_t srr_off    = zero_sz;
    const size_t f2bf_off   = srr_off + 4096;
    const size_t f2bf_sz    = (size_t)BB * DD * 2;        // 256 KB
    const size_t qbf_off    = f2bf_off + f2bf_sz;
    const size_t qbf_sz     = (size_t)QQ * DD * 2;        // 16 MB
    const size_t qlabn_off  = qbf_off + qbf_sz;
    const size_t total_pre  = qlabn_off + (size_t)QQ * 4;

    const bool pre = ws_size >= total_pre;

    int*   cnt    = (int*)(ws + cnt_off);
    float* scal   = (float*)(ws + scal_off);
    int*   ticket = (int*)(ws + ticket_off);
    float* rowacc = (float*)(ws + rowacc_off);
    float* srr    = (float*)(ws + srr_off);
    unsigned short* f2bf = pre ? (unsigned short*)(ws + f2bf_off) : nullptr;
    unsigned short* qbf  = pre ? (unsigned short*)(ws + qbf_off) : nullptr;
    int* qlabn           = pre ? (int*)(ws + qlabn_off) : nullptr;

    hipMemsetAsync(ws, 0, zero_sz, stream);

    if (pre)
        k1_conv<1><<<dim3(516), dim3(256), 0, stream>>>(
            features, labels, queue, queue_labels, qbf, qlabn, f2bf, cnt, srr);
    else
        k1_conv<0><<<dim3(516), dim3(256), 0, stream>>>(
            features, labels, queue, queue_labels, qbf, qlabn, f2bf, cnt, srr);

    dim3 grid(CG * NSLICES);    // 1024 blocks
    if (pre)
        supcon_main<1><<<grid, dim3(THREADS), 0, stream>>>(
            features, labels, queue, queue_labels, qbf, qlabn, f2bf, rowacc);
    else
        supcon_main<0><<<grid, dim3(THREADS), 0, stream>>>(
            features, labels, queue, queue_labels, qbf, qlabn, f2bf, rowacc);

    f_finish<<<dim3(4), dim3(256), 0, stream>>>(
        rowacc, srr, cnt, labels, scal, ticket, (float*)d_out);
}